// Round 1
// baseline (3082.432 us; speedup 1.0000x reference)
//
#include <hip/hip_runtime.h>
#include <hip/hip_bf16.h>

// Problem constants (from reference): B=256, T=512, D=64, H=256, C=10
#define Bsz 256
#define Tt  512
#define Dd  64
#define Hh  256
#define KT  320   // H + D
#define CC  10

typedef short  short8 __attribute__((ext_vector_type(8)));
typedef __bf16 bf16x8 __attribute__((ext_vector_type(8)));
typedef float  f32x4  __attribute__((ext_vector_type(4)));

__device__ __forceinline__ unsigned short f2bf(float f) {
    unsigned u = __builtin_bit_cast(unsigned, f);
    u += 0x7fffu + ((u >> 16) & 1u);   // RNE (inputs are finite/normal)
    return (unsigned short)(u >> 16);
}
__device__ __forceinline__ float bf2f(unsigned short s) {
    unsigned u = ((unsigned)s) << 16;
    return __builtin_bit_cast(float, u);
}
__device__ __forceinline__ float sigf(float x) { return 1.0f / (1.0f + expf(-x)); }

// ---------------------------------------------------------------------------
// Pre-permute weights into per-lane MFMA B-fragment order (bf16).
// Fragment linear layout: elem index = ((nf*10 + ks)*64 + lane)*8 + j
//   nf = nc16*4 + gate   (nc16 = 16-col chunk of H, gate in {i,f,g,o})
//   k  = ks*32 + (lane>>4)*8 + j   (K = 320: k<256 -> W_hh, else W_ih)
//   col= lane & 15  -> n_orig = gate*256 + nc16*16 + col
// ---------------------------------------------------------------------------
__global__ void prep_weights(const float* __restrict__ W_ih,
                             const float* __restrict__ W_hh,
                             unsigned short* __restrict__ Wc) {
    int id = blockIdx.x * blockDim.x + threadIdx.x;   // 0 .. 327679
    int j    = id & 7;
    int lane = (id >> 3) & 63;
    int rest = id >> 9;            // 0..639
    int ks   = rest % 10;
    int nf   = rest / 10;
    int k    = ks * 32 + ((lane >> 4) << 3) + j;
    int col  = lane & 15;
    int nc16 = nf >> 2;
    int g    = nf & 3;
    int n_orig = g * 256 + nc16 * 16 + col;
    float v = (k < 256) ? W_hh[n_orig * 256 + k]
                        : W_ih[n_orig * 64 + (k - 256)];
    Wc[id] = f2bf(v);
}

// biasp[nf*16 + col] = b_ih[n_orig] + b_hh[n_orig]; also zero h0 and c.
__global__ void prep_bias_init(const float* __restrict__ b_ih,
                               const float* __restrict__ b_hh,
                               float* __restrict__ biasp,
                               unsigned short* __restrict__ h0,
                               float* __restrict__ c) {
    int tid = blockIdx.x * blockDim.x + threadIdx.x;  // 65536 threads
    if (tid < 1024) {
        int nf = tid >> 4, col = tid & 15;
        int nc16 = nf >> 2, g = nf & 3;
        int n_orig = g * 256 + nc16 * 16 + col;
        biasp[tid] = b_ih[n_orig] + b_hh[n_orig];
    }
    h0[tid] = 0;       // h = 0
    c[tid]  = 0.0f;    // c = 0
}

// ---------------------------------------------------------------------------
// One LSTM timestep. Grid: 64 WGs = 8 M-tiles (32 batch rows) x 8 col-tiles
// (32 h-cols). Block: 256 threads = 4 waves; wave w handles rows
// rb = mt*32+(w&1)*16 and 16-col chunk nc16 = qt*2+(w>>1), ALL 4 gates.
// z = [h | x_t] @ Wc (K=320) + bias, then gate math; wave-local c/h update.
// hin/hout double-buffered across steps (cross-WG RAW hazard).
// ---------------------------------------------------------------------------
__global__ __launch_bounds__(256) void lstm_step(
    const float* __restrict__ x,
    const unsigned short* __restrict__ Wc,
    const float* __restrict__ biasp,
    const unsigned short* __restrict__ hin,
    unsigned short* __restrict__ hout,
    float* __restrict__ c,
    int t)
{
    const int lane = threadIdx.x & 63;
    const int w    = threadIdx.x >> 6;
    const int mt   = blockIdx.x >> 3;
    const int qt   = blockIdx.x & 7;
    const int rb   = mt * 32 + (w & 1) * 16;
    const int nc16 = qt * 2 + (w >> 1);
    const int colbase = nc16 * 16;
    const int l15 = lane & 15;
    const int lhi = lane >> 4;

    f32x4 acc[4];
    #pragma unroll
    for (int g = 0; g < 4; ++g) {
        float bg = biasp[(nc16 * 4 + g) * 16 + l15];
        acc[g] = (f32x4){bg, bg, bg, bg};
    }

    const int arow = rb + l15;   // A-fragment row (batch index)

    #pragma unroll
    for (int ks = 0; ks < 10; ++ks) {
        short8 a;
        if (ks < 8) {
            // h part of K: h[arow, ks*32 + lhi*8 .. +8) as bf16
            a = *reinterpret_cast<const short8*>(hin + arow * 256 + ks * 32 + lhi * 8);
        } else {
            // x part of K: x[arow, t, d0..d0+8) fp32 -> bf16
            const float* xp = x + arow * (Tt * Dd) + t * Dd + (ks - 8) * 32 + lhi * 8;
            float4 x0 = *reinterpret_cast<const float4*>(xp);
            float4 x1 = *reinterpret_cast<const float4*>(xp + 4);
            a = (short8){ (short)f2bf(x0.x), (short)f2bf(x0.y),
                          (short)f2bf(x0.z), (short)f2bf(x0.w),
                          (short)f2bf(x1.x), (short)f2bf(x1.y),
                          (short)f2bf(x1.z), (short)f2bf(x1.w) };
        }
        bf16x8 av = __builtin_bit_cast(bf16x8, a);
        #pragma unroll
        for (int g = 0; g < 4; ++g) {
            short8 b = *reinterpret_cast<const short8*>(
                Wc + (((nc16 * 4 + g) * 10 + ks) * 64 + lane) * 8);
            acc[g] = __builtin_amdgcn_mfma_f32_16x16x32_bf16(
                av, __builtin_bit_cast(bf16x8, b), acc[g], 0, 0, 0);
        }
    }

    // Epilogue: C/D layout col = lane&15, row = (lane>>4)*4 + r  (m89-verified)
    #pragma unroll
    for (int r = 0; r < 4; ++r) {
        int row = rb + lhi * 4 + r;
        int idx = (row << 8) + colbase + l15;
        float zi = acc[0][r];
        float zf = acc[1][r];
        float zg = acc[2][r];
        float zo = acc[3][r];
        float cn = sigf(zf) * c[idx] + sigf(zi) * tanhf(zg);
        float hn = sigf(zo) * tanhf(cn);
        c[idx]   = cn;
        hout[idx] = f2bf(hn);
    }
}

// ---------------------------------------------------------------------------
// Output head: out[b, cc] = sigmoid(h[b,:] . W_out[cc,:] + b_out[cc])
// One wave per batch row; shuffle-reduce per class.
// ---------------------------------------------------------------------------
__global__ void lstm_out(const unsigned short* __restrict__ hT,
                         const float* __restrict__ W_out,
                         const float* __restrict__ b_out,
                         float* __restrict__ out) {
    int b    = blockIdx.x;
    int lane = threadIdx.x;  // 64
    ushort4 hu = *reinterpret_cast<const ushort4*>(hT + b * 256 + lane * 4);
    float hv0 = bf2f(hu.x), hv1 = bf2f(hu.y), hv2 = bf2f(hu.z), hv3 = bf2f(hu.w);
    for (int cc = 0; cc < CC; ++cc) {
        float4 wv = *reinterpret_cast<const float4*>(W_out + cc * 256 + lane * 4);
        float p = hv0 * wv.x + hv1 * wv.y + hv2 * wv.z + hv3 * wv.w;
        #pragma unroll
        for (int off = 32; off > 0; off >>= 1) p += __shfl_down(p, off);
        if (lane == 0) out[b * CC + cc] = sigf(p + b_out[cc]);
    }
}

extern "C" void kernel_launch(void* const* d_in, const int* in_sizes, int n_in,
                              void* d_out, int out_size, void* d_ws, size_t ws_size,
                              hipStream_t stream) {
    const float* x     = (const float*)d_in[0];
    const float* W_ih  = (const float*)d_in[1];
    const float* W_hh  = (const float*)d_in[2];
    const float* b_ih  = (const float*)d_in[3];
    const float* b_hh  = (const float*)d_in[4];
    const float* W_out = (const float*)d_in[5];
    const float* b_out = (const float*)d_in[6];
    float* out = (float*)d_out;

    // workspace layout (1.13 MB total)
    char* ws = (char*)d_ws;
    unsigned short* Wc    = (unsigned short*)(ws);            // 655360 B
    float*          biasp = (float*)(ws + 655360);            //   4096 B
    unsigned short* h0    = (unsigned short*)(ws + 659456);   // 131072 B
    unsigned short* h1    = (unsigned short*)(ws + 790528);   // 131072 B
    float*          cbuf  = (float*)(ws + 921600);            // 262144 B

    hipLaunchKernelGGL(prep_weights, dim3(1280), dim3(256), 0, stream, W_ih, W_hh, Wc);
    hipLaunchKernelGGL(prep_bias_init, dim3(256), dim3(256), 0, stream,
                       b_ih, b_hh, biasp, h0, cbuf);

    unsigned short* hb[2] = {h0, h1};
    for (int t = 0; t < Tt; ++t) {
        hipLaunchKernelGGL(lstm_step, dim3(64), dim3(256), 0, stream,
                           x, Wc, biasp, hb[t & 1], hb[(t + 1) & 1], cbuf, t);
    }
    // t=511 wrote hb[0]
    hipLaunchKernelGGL(lstm_out, dim3(256), dim3(64), 0, stream, h0, W_out, b_out, out);
}

// Round 2
// 2881.289 us; speedup vs baseline: 1.0698x; 1.0698x over previous
//
#include <hip/hip_runtime.h>
#include <hip/hip_bf16.h>

// Problem constants: B=256, T=512, D=64, H=256, C=10
#define Tt  512
#define Dd  64
#define CC  10

typedef short  short8 __attribute__((ext_vector_type(8)));
typedef __bf16 bf16x8 __attribute__((ext_vector_type(8)));
typedef float  f32x4  __attribute__((ext_vector_type(4)));

__device__ __forceinline__ unsigned short f2bf(float f) {
    unsigned u = __builtin_bit_cast(unsigned, f);
    u += 0x7fffu + ((u >> 16) & 1u);   // RNE
    return (unsigned short)(u >> 16);
}
__device__ __forceinline__ float bf2f(unsigned short s) {
    unsigned u = ((unsigned)s) << 16;
    return __builtin_bit_cast(float, u);
}
__device__ __forceinline__ float sigf(float x) {
    return __builtin_amdgcn_rcpf(1.0f + __expf(-x));
}
__device__ __forceinline__ float tanh_fast(float x) {
    // tanh(x) = 1 - 2/(exp(2x)+1); saturates correctly at +/-inf
    return 1.0f - 2.0f * __builtin_amdgcn_rcpf(1.0f + __expf(2.0f * x));
}

// ---------------------------------------------------------------------------
// Pre-permute weights into per-lane MFMA B-fragment order (bf16).
// elem index = ((nf*10 + ks)*64 + lane)*8 + j
//   nf = nc16*4 + gate;  k = ks*32 + (lane>>4)*8 + j  (k<256 -> W_hh else W_ih)
//   col = lane&15 -> n_orig = gate*256 + nc16*16 + col
// ---------------------------------------------------------------------------
__global__ void prep_weights(const float* __restrict__ W_ih,
                             const float* __restrict__ W_hh,
                             unsigned short* __restrict__ Wc) {
    int id = blockIdx.x * blockDim.x + threadIdx.x;   // 0 .. 327679
    int j    = id & 7;
    int lane = (id >> 3) & 63;
    int rest = id >> 9;            // 0..639
    int ks   = rest % 10;
    int nf   = rest / 10;
    int k    = ks * 32 + ((lane >> 4) << 3) + j;
    int col  = lane & 15;
    int nc16 = nf >> 2;
    int g    = nf & 3;
    int n_orig = g * 256 + nc16 * 16 + col;
    float v = (k < 256) ? W_hh[n_orig * 256 + k]
                        : W_ih[n_orig * 64 + (k - 256)];
    Wc[id] = f2bf(v);
}

__global__ void prep_bias(const float* __restrict__ b_ih,
                          const float* __restrict__ b_hh,
                          float* __restrict__ biasp) {
    int tid = blockIdx.x * blockDim.x + threadIdx.x;  // 1024 threads
    if (tid < 1024) {
        int nf = tid >> 4, col = tid & 15;
        int nc16 = nf >> 2, g = nf & 3;
        int n_orig = g * 256 + nc16 * 16 + col;
        biasp[tid] = b_ih[n_orig] + b_hh[n_orig];
    }
}

// ---------------------------------------------------------------------------
// Persistent LSTM: 64 WGs = 8 row-groups (32 batch rows) x 8 col-chunks
// (32 h-cols, all 4 gates). 256 thr = 4 waves; wave w: rows rb=rg*32+(w&1)*16,
// nc16 = q*2+(w>>1). Weights held in VGPRs; c in registers; h exchanged via
// global double-buffer with per-row-group arrival counters (agent scope).
// ---------------------------------------------------------------------------
__global__ __launch_bounds__(256, 1) void lstm_persist(
    const float* __restrict__ x,
    const unsigned short* __restrict__ Wc,
    const float* __restrict__ biasp,
    unsigned short* __restrict__ h0buf,
    unsigned short* __restrict__ h1buf,
    unsigned int* __restrict__ arrive,
    const float* __restrict__ W_out,
    const float* __restrict__ b_out,
    float* __restrict__ out)
{
    const int tid  = threadIdx.x;
    const int lane = tid & 63;
    const int w    = tid >> 6;
    const int rg   = blockIdx.x >> 3;   // row group 0..7
    const int q    = blockIdx.x & 7;    // col chunk 0..7
    const int l15  = lane & 15;
    const int lhi  = lane >> 4;

    const int rb      = rg * 32 + (w & 1) * 16;
    const int nc16    = q * 2 + (w >> 1);
    const int colbase = nc16 * 16;
    const int arow    = rb + l15;

    // --- one-time: B fragments (constant over t) into registers ---
    bf16x8 bfrag[10][4];
    #pragma unroll
    for (int ks = 0; ks < 10; ++ks)
        #pragma unroll
        for (int g = 0; g < 4; ++g)
            bfrag[ks][g] = __builtin_bit_cast(bf16x8,
                *reinterpret_cast<const short8*>(
                    Wc + (((nc16 * 4 + g) * 10 + ks) * 64 + lane) * 8));

    float bias_r[4];
    #pragma unroll
    for (int g = 0; g < 4; ++g) bias_r[g] = biasp[(nc16 * 4 + g) * 16 + l15];

    f32x4 creg = (f32x4){0.f, 0.f, 0.f, 0.f};

    unsigned int* cnt = arrive + rg * 32;           // 128 B apart per rg
    const float* xrow = x + (size_t)arow * (Tt * Dd);
    unsigned short* hbufs[2] = { h0buf, h1buf };

    for (int t = 0; t < Tt; ++t) {
        f32x4 acc[4];
        #pragma unroll
        for (int g = 0; g < 4; ++g)
            acc[g] = (f32x4){bias_r[g], bias_r[g], bias_r[g], bias_r[g]};

        // --- x contribution (ks=8,9) BEFORE the wait -----------------------
        {
            const float* xp = xrow + t * Dd + lhi * 8;
            float4 x0 = *reinterpret_cast<const float4*>(xp);
            float4 x1 = *reinterpret_cast<const float4*>(xp + 4);
            float4 x2 = *reinterpret_cast<const float4*>(xp + 32);
            float4 x3 = *reinterpret_cast<const float4*>(xp + 36);
            short8 a8 = (short8){ (short)f2bf(x0.x), (short)f2bf(x0.y),
                                  (short)f2bf(x0.z), (short)f2bf(x0.w),
                                  (short)f2bf(x1.x), (short)f2bf(x1.y),
                                  (short)f2bf(x1.z), (short)f2bf(x1.w) };
            short8 a9 = (short8){ (short)f2bf(x2.x), (short)f2bf(x2.y),
                                  (short)f2bf(x2.z), (short)f2bf(x2.w),
                                  (short)f2bf(x3.x), (short)f2bf(x3.y),
                                  (short)f2bf(x3.z), (short)f2bf(x3.w) };
            bf16x8 av8 = __builtin_bit_cast(bf16x8, a8);
            bf16x8 av9 = __builtin_bit_cast(bf16x8, a9);
            #pragma unroll
            for (int g = 0; g < 4; ++g) {
                acc[g] = __builtin_amdgcn_mfma_f32_16x16x32_bf16(av8, bfrag[8][g], acc[g], 0, 0, 0);
                acc[g] = __builtin_amdgcn_mfma_f32_16x16x32_bf16(av9, bfrag[9][g], acc[g], 0, 0, 0);
            }
        }

        // --- wait for h_t, then recurrent contribution (ks=0..7) -----------
        if (t > 0) {
            const unsigned target = 8u * (unsigned)t;
            if (lane == 0) {
                while (__hip_atomic_load(cnt, __ATOMIC_RELAXED,
                                         __HIP_MEMORY_SCOPE_AGENT) < target) {}
            }
            __builtin_amdgcn_fence(__ATOMIC_ACQUIRE, "agent");
            const unsigned short* hin = hbufs[t & 1];
            short8 af[8];
            #pragma unroll
            for (int ks = 0; ks < 8; ++ks)
                af[ks] = *reinterpret_cast<const short8*>(
                    hin + arow * 256 + ks * 32 + lhi * 8);
            #pragma unroll
            for (int ks = 0; ks < 8; ++ks) {
                bf16x8 av = __builtin_bit_cast(bf16x8, af[ks]);
                #pragma unroll
                for (int g = 0; g < 4; ++g)
                    acc[g] = __builtin_amdgcn_mfma_f32_16x16x32_bf16(
                        av, bfrag[ks][g], acc[g], 0, 0, 0);
            }
        }

        // --- gates + c/h update (c persistent in registers) ----------------
        unsigned short* hout = hbufs[(t + 1) & 1];
        #pragma unroll
        for (int r = 0; r < 4; ++r) {
            float cn = sigf(acc[1][r]) * creg[r] + sigf(acc[0][r]) * tanh_fast(acc[2][r]);
            float hn = sigf(acc[3][r]) * tanh_fast(cn);
            creg[r] = cn;
            int row = rb + lhi * 4 + r;
            hout[(row << 8) + colbase + l15] = f2bf(hn);
        }

        // --- publish: drain WG stores, release, arrive ----------------------
        __syncthreads();
        if (tid == 0) {
            __builtin_amdgcn_fence(__ATOMIC_RELEASE, "agent");
            __hip_atomic_fetch_add(cnt, 1u, __ATOMIC_RELAXED,
                                   __HIP_MEMORY_SCOPE_AGENT);
        }
    }

    // --- output head: q==0 WGs handle their 32 rows ------------------------
    if (q == 0) {
        if (lane == 0) {
            while (__hip_atomic_load(cnt, __ATOMIC_RELAXED,
                                     __HIP_MEMORY_SCOPE_AGENT) < 8u * Tt) {}
        }
        __builtin_amdgcn_fence(__ATOMIC_ACQUIRE, "agent");
        const unsigned short* hT = h0buf;   // Tt even -> final h in buf 0
        #pragma unroll 1
        for (int rr = 0; rr < 8; ++rr) {
            int row = rg * 32 + w * 8 + rr;
            ushort4 hu = *reinterpret_cast<const ushort4*>(hT + row * 256 + lane * 4);
            float h0 = bf2f(hu.x), h1 = bf2f(hu.y), h2 = bf2f(hu.z), h3 = bf2f(hu.w);
            #pragma unroll 1
            for (int cls = 0; cls < CC; ++cls) {
                float4 wv = *reinterpret_cast<const float4*>(W_out + cls * 256 + lane * 4);
                float p = h0 * wv.x + h1 * wv.y + h2 * wv.z + h3 * wv.w;
                #pragma unroll
                for (int off = 32; off > 0; off >>= 1) p += __shfl_down(p, off);
                if (lane == 0) out[row * CC + cls] = sigf(p + b_out[cls]);
            }
        }
    }
}

extern "C" void kernel_launch(void* const* d_in, const int* in_sizes, int n_in,
                              void* d_out, int out_size, void* d_ws, size_t ws_size,
                              hipStream_t stream) {
    const float* x     = (const float*)d_in[0];
    const float* W_ih  = (const float*)d_in[1];
    const float* W_hh  = (const float*)d_in[2];
    const float* b_ih  = (const float*)d_in[3];
    const float* b_hh  = (const float*)d_in[4];
    const float* W_out = (const float*)d_in[5];
    const float* b_out = (const float*)d_in[6];
    float* out = (float*)d_out;

    // workspace layout (~923 KB)
    char* ws = (char*)d_ws;
    unsigned short* Wc    = (unsigned short*)(ws);            // 655360 B
    float*          biasp = (float*)(ws + 655360);            //   4096 B
    unsigned short* h0    = (unsigned short*)(ws + 659456);   // 131072 B
    unsigned short* h1    = (unsigned short*)(ws + 790528);   // 131072 B
    unsigned int*   arr   = (unsigned int*)(ws + 921600);     //   1024 B

    hipLaunchKernelGGL(prep_weights, dim3(1280), dim3(256), 0, stream, W_ih, W_hh, Wc);
    hipLaunchKernelGGL(prep_bias,    dim3(4),    dim3(256), 0, stream, b_ih, b_hh, biasp);
    hipMemsetAsync(arr, 0, 1024, stream);

    hipLaunchKernelGGL(lstm_persist, dim3(64), dim3(256), 0, stream,
                       x, Wc, biasp, h0, h1, arr, W_out, b_out, out);
}